// Round 6
// baseline (259.030 us; speedup 1.0000x reference)
//
#include <hip/hip_runtime.h>
#include <hip/hip_fp16.h>

#define HH 256
#define WW 256
#define KK 81
#define PLANE (HH * WW)
#define SLACK 10          // tile halo: rows [ho-10, ho+10], cols [xb, xb+83]
#define TR 21             // tile rows
#define TC 84             // tile cols (64-px strip + 4+SLACK halo each side)
#define TAB (TR * TC)     // 1764 cells per plane

// Pack [B,3,H,W] fp32 -> [B,H,W] ushort4 of fp16 (c0,c1,c2,0).
__global__ __launch_bounds__(256) void pack_kernel(const float* __restrict__ in,
                                                   ushort4* __restrict__ img) {
    int idx = blockIdx.x * 256 + threadIdx.x;  // b*PLANE + pix
    int b = idx >> 16;
    int pix = idx & 0xFFFF;
    const float* base = in + (size_t)b * 3 * PLANE + pix;
    _Float16 h0 = (_Float16)base[0];
    _Float16 h1 = (_Float16)base[PLANE];
    _Float16 h2 = (_Float16)base[2 * PLANE];
    ushort4 u;
    u.x = __builtin_bit_cast(unsigned short, h0);
    u.y = __builtin_bit_cast(unsigned short, h1);
    u.z = __builtin_bit_cast(unsigned short, h2);
    u.w = 0;
    img[idx] = u;
}

__device__ __forceinline__ void acc3(float w, unsigned int pa, unsigned int pb,
                                     float& ax, float& ay, float& az) {
    __half2 ha = __builtin_bit_cast(__half2, pa);
    __half2 hb = __builtin_bit_cast(__half2, pb);
    ax = fmaf(w, __low2float(ha), ax);   // v_fma_mix_f32 (lo)
    ay = fmaf(w, __high2float(ha), ay);  // v_fma_mix_f32 (hi)
    az = fmaf(w, __low2float(hb), az);
}

// Block = 64-pixel strip of one output row. 4 waves split the 81 taps
// (21/21/21/21 with tap 20 masked on waves 1-3) and LDS-reduce. Input tile
// staged ZERO-PADDED in LDS as two 4 B planes. Each wave prefetches ALL its
// dy/dx/m (63 dwords) into registers before the compute phase: one exposed
// HBM latency per wave instead of five.
__global__ __launch_bounds__(256, 4) void dcn_kernel(
    const ushort4* __restrict__ img,
    const float* __restrict__ offset,
    const float* __restrict__ mask,
    const float* __restrict__ weight,
    const float* __restrict__ bias,
    float* __restrict__ out) {
    __shared__ unsigned int tile2[2 * TAB + 96];  // [0,TAB): c0c1  [TAB,2TAB): c2
    __shared__ float red[3][4][64];
    __shared__ float wk[KK];

    const int t = threadIdx.x;
    if (t < KK) wk[t] = weight[t];

    const int b = blockIdx.y;
    const int pix0 = blockIdx.x * 64;
    const int ho = pix0 >> 8;                 // strip stays in one output row
    const int xb = (pix0 & 255) - SLACK;
    const int yb = ho - SLACK;
    const ushort4* ib = img + (size_t)b * PLANE;

    const int w = t >> 6;
    const int lane = t & 63;
    const int wo = (pix0 & 255) + lane;
    const int pix = pix0 + lane;
    const int kb = w * 20 + (w ? 1 : 0);      // 0,21,41,61

    // ---- prefetch phase: issue all 63 streaming loads first ----
    const float* ob = offset + (size_t)b * 2 * KK * PLANE + pix;
    const float* mb = mask + (size_t)b * KK * PLANE + pix;
    float dyv[21], dxv[21], mv[21];
#pragma unroll
    for (int i = 0; i < 21; ++i) {
        int kc = kb + i;
        if (kc > 80) kc = 80;                 // wave-uniform clamp (stays in-bounds)
        dyv[i] = ob[(size_t)(2 * kc) * PLANE];
        dxv[i] = ob[(size_t)(2 * kc + 1) * PLANE];
        mv[i] = mb[(size_t)kc * PLANE];
    }

    // ---- stage tile (overlaps the prefetch latency): zero outside image ----
    for (int i = 0; i < 7; ++i) {
        int cid = t + i * 256;
        if (cid < TAB) {
            int r = cid / TC;
            int c = cid - r * TC;
            int iy = yb + r;
            int ix = xb + c;
            unsigned int pa = 0, pb = 0;
            if (((unsigned)iy < (unsigned)HH) & ((unsigned)ix < (unsigned)WW)) {
                ushort4 u = ib[iy * WW + ix];
                pa = (unsigned int)u.x | ((unsigned int)u.y << 16);
                pb = (unsigned int)u.z;
            }
            tile2[cid] = pa;
            tile2[cid + TAB] = pb;
        }
    }
    __syncthreads();

    const float wof = (float)wo;
    float ax = 0.f, ay = 0.f, az = 0.f;

    // ---- compute phase ----
#pragma unroll
    for (int i = 0; i < 21; ++i) {
        int kc = kb + i;
        if (kc > 80) kc = 80;
        const int ky = kc / 9;
        const int kx = kc - ky * 9;

        float m = mv[i] * wk[kc];
        if (i == 20 && w != 0) m = 0.f;       // duplicate tap masked out
        float dy = dyv[i];
        float dx = dxv[i];

        float py = (float)(ho - 4 + ky) + dy;
        float px = wof + ((float)(kx - 4) + dx);
        float y0f = floorf(py), x0f = floorf(px);
        float wy = py - y0f, wx = px - x0f;
        int y0 = (int)y0f, x0 = (int)x0f;

        // unclamped tile coords: tile row r == image row yb+r (zero-padded)
        int r0 = y0 - yb;
        int c0 = x0 - xb;
        bool ok = ((unsigned)r0 < (TR - 1)) & ((unsigned)c0 < (TC - 1));

        float w1y = wy * m, w0y = m - w1y;
        float w00 = w0y * (1.f - wx), w01 = w0y * wx;
        float w10 = w1y * (1.f - wx), w11 = w1y * wx;

        unsigned int pa00, pa01, pa10, pa11, pb00, pb01, pb10, pb11;
        if (__builtin_expect(__all(ok), 1)) {
            int i00 = r0 * TC + c0;
            pa00 = tile2[i00];
            pa01 = tile2[i00 + 1];
            pa10 = tile2[i00 + TC];
            pa11 = tile2[i00 + TC + 1];
            pb00 = tile2[i00 + TAB];
            pb01 = tile2[i00 + TAB + 1];
            pb10 = tile2[i00 + TAB + TC];
            pb11 = tile2[i00 + TAB + TC + 1];
        } else {
            if (ok) {
                int i00 = r0 * TC + c0;
                pa00 = tile2[i00];
                pa01 = tile2[i00 + 1];
                pa10 = tile2[i00 + TC];
                pa11 = tile2[i00 + TC + 1];
                pb00 = tile2[i00 + TAB];
                pb01 = tile2[i00 + TAB + 1];
                pb10 = tile2[i00 + TAB + TC];
                pb11 = tile2[i00 + TAB + TC + 1];
            } else {
                // fully clamped + validity-masked global fallback (cold)
                int y1 = y0 + 1, x1 = x0 + 1;
                float va0 = ((unsigned)y0 < (unsigned)HH) ? 1.f : 0.f;
                float va1 = ((unsigned)y1 < (unsigned)HH) ? 1.f : 0.f;
                float vb0 = ((unsigned)x0 < (unsigned)WW) ? 1.f : 0.f;
                float vb1 = ((unsigned)x1 < (unsigned)WW) ? 1.f : 0.f;
                w00 *= va0 * vb0;
                w01 *= va0 * vb1;
                w10 *= va1 * vb0;
                w11 *= va1 * vb1;
                int y0c = min(max(y0, 0), HH - 1);
                int y1c = min(max(y1, 0), HH - 1);
                int x0c = min(max(x0, 0), WW - 1);
                int x1c = min(max(x1, 0), WW - 1);
                ushort4 g00 = ib[y0c * WW + x0c];
                ushort4 g01 = ib[y0c * WW + x1c];
                ushort4 g10 = ib[y1c * WW + x0c];
                ushort4 g11 = ib[y1c * WW + x1c];
                pa00 = (unsigned int)g00.x | ((unsigned int)g00.y << 16); pb00 = g00.z;
                pa01 = (unsigned int)g01.x | ((unsigned int)g01.y << 16); pb01 = g01.z;
                pa10 = (unsigned int)g10.x | ((unsigned int)g10.y << 16); pb10 = g10.z;
                pa11 = (unsigned int)g11.x | ((unsigned int)g11.y << 16); pb11 = g11.z;
            }
        }

        acc3(w00, pa00, pb00, ax, ay, az);
        acc3(w01, pa01, pb01, ax, ay, az);
        acc3(w10, pa10, pb10, ax, ay, az);
        acc3(w11, pa11, pb11, ax, ay, az);
    }

    red[0][w][lane] = ax;
    red[1][w][lane] = ay;
    red[2][w][lane] = az;
    __syncthreads();

    if (t < 192) {
        const int c = t >> 6;
        const int l = t & 63;
        float s = red[c][0][l] + red[c][1][l] + red[c][2][l] + red[c][3][l] + bias[0];
        out[(size_t)b * 3 * PLANE + (size_t)c * PLANE + pix0 + l] = s;
    }
}

extern "C" void kernel_launch(void* const* d_in, const int* in_sizes, int n_in,
                              void* d_out, int out_size, void* d_ws, size_t ws_size,
                              hipStream_t stream) {
    const float* input = (const float*)d_in[0];
    const float* offset = (const float*)d_in[1];
    const float* mask = (const float*)d_in[2];
    const float* weight = (const float*)d_in[3];
    const float* bias = (const float*)d_in[4];
    float* out = (float*)d_out;

    const int B = in_sizes[0] / (3 * PLANE);  // 2
    ushort4* img = (ushort4*)d_ws;            // 1 MB packed fp16 image

    pack_kernel<<<B * PLANE / 256, 256, 0, stream>>>(input, img);
    dim3 grid(PLANE / 64, B);
    dcn_kernel<<<grid, 256, 0, stream>>>(img, offset, mask, weight, bias, out);
}